// Round 1
// baseline (1412.810 us; speedup 1.0000x reference)
//
#include <hip/hip_runtime.h>

#define BB 2
#define LL 512
#define DD 64
#define HH 8
#define GG 64
#define KK 4
#define NEGV -1e9f

// distance-table index for delta = i - j (clip to [-4,4], torch negative wrap)
__device__ __forceinline__ int tdx(int delta) {
    delta = delta < -4 ? -4 : (delta > 4 ? 4 : delta);
    return delta < 0 ? delta + 9 : delta;
}

#define LD4(arr, r, c_) (*reinterpret_cast<const float4*>(&(arr)[r][c_]))

// ---------------- K1: Q_z = softmax(q_z) over d=64; one wave per row ----------------
__global__ void k_softmax_qz(const float* __restrict__ src, float* __restrict__ Qz) {
    int row = blockIdx.x * 4 + (threadIdx.x >> 6);   // B*L = 1024 rows
    int lane = threadIdx.x & 63;
    float v = src[row * DD + lane];
    float m = v;
#pragma unroll
    for (int o = 32; o > 0; o >>= 1) m = fmaxf(m, __shfl_xor(m, o, 64));
    float e = __expf(v - m);
    float s = e;
#pragma unroll
    for (int o = 32; o > 0; o >>= 1) s += __shfl_xor(s, o, 64);
    Qz[row * DD + lane] = e / s;
}

// ---------------- K2: M1/M2 tensor messages ----------------
// M1[z,k,j,a,c] = sum_b Qz[z,j,b] T[k,a,b,c];  M2 swaps a/b roles.
// Stores: M1N [z,k,c,j,a], M2N [z,k,c,j,a], M1T [z,k,c,a,j]
__global__ void k_compute_M(const float* __restrict__ Qz, const float* __restrict__ T,
                            float* __restrict__ M1T, float* __restrict__ M1N,
                            float* __restrict__ M2N) {
    int jt = blockIdx.x;            // 8 j-tiles of 64
    int c  = blockIdx.y;            // 8
    int z  = blockIdx.z >> 2;       // 2
    int k  = blockIdx.z & 3;        // 4
    __shared__ __align__(16) float sQ[64][68];
    __shared__ __align__(16) float sT1[64][68];   // [b][a] = T[k,a,b,c]
    __shared__ __align__(16) float sT2[64][68];   // [b][a] = T[k,b,a,c]
    int tid = threadIdx.x;
    for (int idx = tid; idx < 4096; idx += 256) {
        int a = idx >> 6, b = idx & 63;
        sT1[b][a] = T[(((k * 64 + a) * 64 + b) << 3) + c];
        sT2[b][a] = T[(((k * 64 + b) * 64 + a) << 3) + c];
        sQ[a][b]  = Qz[(z * LL + jt * 64 + a) * DD + b];   // a reused as jj here
    }
    __syncthreads();
    int jj = tid >> 2;
    int a0 = (tid & 3) << 4;
    float m1[16], m2[16];
#pragma unroll
    for (int r = 0; r < 16; ++r) { m1[r] = 0.f; m2[r] = 0.f; }
    for (int b = 0; b < 64; ++b) {
        float q = sQ[jj][b];
#pragma unroll
        for (int u = 0; u < 4; ++u) {
            float4 t1 = LD4(sT1, b, a0 + u * 4);
            float4 t2 = LD4(sT2, b, a0 + u * 4);
            m1[u*4+0] += q * t1.x; m1[u*4+1] += q * t1.y; m1[u*4+2] += q * t1.z; m1[u*4+3] += q * t1.w;
            m2[u*4+0] += q * t2.x; m2[u*4+1] += q * t2.y; m2[u*4+2] += q * t2.z; m2[u*4+3] += q * t2.w;
        }
    }
    int j = jt * 64 + jj;
    size_t base = ((((size_t)z * KK + k) * HH + c) * LL + j) * DD + a0;
#pragma unroll
    for (int u = 0; u < 4; ++u) {
        *reinterpret_cast<float4*>(&M1N[base + u * 4]) =
            make_float4(m1[u*4+0], m1[u*4+1], m1[u*4+2], m1[u*4+3]);
        *reinterpret_cast<float4*>(&M2N[base + u * 4]) =
            make_float4(m2[u*4+0], m2[u*4+1], m2[u*4+2], m2[u*4+3]);
    }
    size_t baseT = ((((size_t)z * KK + k) * HH + c) * DD + a0) * LL + j;
#pragma unroll
    for (int r = 0; r < 16; ++r) M1T[baseT + (size_t)r * LL] = m1[r];
}

// ---------------- K3a: s_h[z,c,i,j] = sum_k dm_k(i-j) * (Qz[i,:] . M1T[k,c,:,j]) + mask ----------------
__global__ void k_sh(const float* __restrict__ Qz, const float* __restrict__ M1T,
                     const float* __restrict__ dp, const int* __restrict__ mask,
                     float* __restrict__ SH) {
    int jt = blockIdx.x, it = blockIdx.y;
    int z = blockIdx.z >> 3, c = blockIdx.z & 7;
    __shared__ __align__(16) float sA[64][68];   // [ii][a]
    __shared__ __align__(16) float sB[64][68];   // [a][jj]
    __shared__ float wt[9][4];
    __shared__ int mrow[64], mcol[64];
    int tid = threadIdx.x;
    if (tid < 36) { int t = tid >> 2, kk = tid & 3; wt[t][kk] = (t == 0) ? 0.f : dp[(t - 1) * 4 + kk]; }
    if (tid >= 64 && tid < 128)  mrow[tid - 64]  = mask[z * LL + it * 64 + (tid - 64)];
    if (tid >= 128 && tid < 192) mcol[tid - 128] = mask[z * LL + jt * 64 + (tid - 128)];
    for (int idx = tid; idx < 4096; idx += 256) {
        int ii = idx >> 6, a = idx & 63;
        sA[ii][a] = Qz[(z * LL + it * 64 + ii) * DD + a];
    }
    int ty = tid >> 4, tx = tid & 15;
    float acc[4][4] = {};
    for (int k = 0; k < KK; ++k) {
        __syncthreads();
        size_t bbase = ((((size_t)z * KK + k) * HH + c) * DD) * LL + jt * 64;
        for (int idx = tid; idx < 4096; idx += 256) {
            int a = idx >> 6, jjl = idx & 63;
            sB[a][jjl] = M1T[bbase + (size_t)a * LL + jjl];
        }
        __syncthreads();
        float tmp[4][4] = {};
        for (int a4 = 0; a4 < 64; a4 += 4) {
            float bvv[4][4];
#pragma unroll
            for (int u = 0; u < 4; ++u) {
                float4 b4 = LD4(sB, a4 + u, tx * 4);
                bvv[u][0] = b4.x; bvv[u][1] = b4.y; bvv[u][2] = b4.z; bvv[u][3] = b4.w;
            }
#pragma unroll
            for (int q = 0; q < 4; ++q) {
                float4 a4v = LD4(sA, ty * 4 + q, a4);
#pragma unroll
                for (int r = 0; r < 4; ++r)
                    tmp[q][r] += a4v.x * bvv[0][r] + a4v.y * bvv[1][r]
                               + a4v.z * bvv[2][r] + a4v.w * bvv[3][r];
            }
        }
#pragma unroll
        for (int q = 0; q < 4; ++q) {
            int i = it * 64 + ty * 4 + q;
#pragma unroll
            for (int r = 0; r < 4; ++r) {
                int j = jt * 64 + tx * 4 + r;
                acc[q][r] += wt[tdx(i - j)][k] * tmp[q][r];
            }
        }
    }
#pragma unroll
    for (int q = 0; q < 4; ++q) {
        int i = it * 64 + ty * 4 + q;
        float vals[4];
#pragma unroll
        for (int r = 0; r < 4; ++r)
            vals[r] = (mrow[ty * 4 + q] && mcol[tx * 4 + r]) ? acc[q][r] : NEGV;
        *reinterpret_cast<float4*>(&SH[(((size_t)z * HH + c) * LL + i) * LL + jt * 64 + tx * 4]) =
            make_float4(vals[0], vals[1], vals[2], vals[3]);
    }
}

// ---------------- K3b: Q_h = softmax over j (512); one wave per row, in place ----------------
__global__ void k_softmax_sh(float* __restrict__ SH) {
    int row = blockIdx.x * 4 + (threadIdx.x >> 6);   // B*H*L = 8192 rows
    int lane = threadIdx.x & 63;
    float v[8];
    float m = -1e30f;
#pragma unroll
    for (int r = 0; r < 8; ++r) { v[r] = SH[(size_t)row * LL + r * 64 + lane]; m = fmaxf(m, v[r]); }
#pragma unroll
    for (int o = 32; o > 0; o >>= 1) m = fmaxf(m, __shfl_xor(m, o, 64));
    float s = 0.f;
#pragma unroll
    for (int r = 0; r < 8; ++r) { v[r] = __expf(v[r] - m); s += v[r]; }
#pragma unroll
    for (int o = 32; o > 0; o >>= 1) s += __shfl_xor(s, o, 64);
    float inv = 1.f / s;
#pragma unroll
    for (int r = 0; r < 8; ++r) SH[(size_t)row * LL + r * 64 + lane] = v[r] * inv;
}

// ---------------- K4: Q_g = softmax_g( Qz . gp^T ), one wave per (z,i) ----------------
__global__ void k_qg(const float* __restrict__ Qz, const float* __restrict__ gp,
                     const int* __restrict__ mask, float* __restrict__ QG) {
    __shared__ __align__(16) float gpS[64][68];   // [g][a]
    int tid = threadIdx.x;
    for (int idx = tid; idx < 4096; idx += 256) gpS[idx >> 6][idx & 63] = gp[idx];
    __syncthreads();
    int row = blockIdx.x * 4 + (tid >> 6);        // B*L
    int g = tid & 63;
    float qv = Qz[row * DD + g];
    float s = 0.f;
    for (int a = 0; a < 64; ++a) s += __shfl(qv, a, 64) * gpS[g][a];
    if (mask[row] == 0) s = NEGV;
    float m = s;
#pragma unroll
    for (int o = 32; o > 0; o >>= 1) m = fmaxf(m, __shfl_xor(m, o, 64));
    float e = __expf(s - m);
    float sum = e;
#pragma unroll
    for (int o = 32; o > 0; o >>= 1) sum += __shfl_xor(sum, o, 64);
    QG[row * GG + g] = e / sum;
}

// ---------------- K5: g1 partials. g1[i,a] = sum_{k,c,j} Qh[c,i,j] dm_k(i-j) M1N[k,c,j,a] ----------------
__global__ void k_g1(const float* __restrict__ SH, const float* __restrict__ M1N,
                     const float* __restrict__ dp, float* __restrict__ PG) {
    int it = blockIdx.x;            // 8 i-tiles
    int jc = blockIdx.y;            // 4 j-chunks of 128
    int z = blockIdx.z >> 3, c = blockIdx.z & 7;
    __shared__ __align__(16) float sQh[64][68];   // [ii][jj]
    __shared__ __align__(16) float sB[64][68];    // [jj][a]
    __shared__ float wt[9][4];
    int tid = threadIdx.x;
    if (tid < 36) { int t = tid >> 2, kk = tid & 3; wt[t][kk] = (t == 0) ? 0.f : dp[(t - 1) * 4 + kk]; }
    int ty = tid >> 4, tx = tid & 15;
    int ibase = it * 64 + ty * 4;
    float acc[4][4] = {};
    for (int js = 0; js < 2; ++js) {
        int j0 = jc * 128 + js * 64;
        __syncthreads();
        for (int idx = tid; idx < 4096; idx += 256) {
            int ii = idx >> 6, jjl = idx & 63;
            sQh[ii][jjl] = SH[(((size_t)z * HH + c) * LL + it * 64 + ii) * LL + j0 + jjl];
        }
        for (int k = 0; k < KK; ++k) {
            __syncthreads();
            for (int idx = tid; idx < 4096; idx += 256) {
                int jjl = idx >> 6, a = idx & 63;
                sB[jjl][a] = M1N[((((size_t)z * KK + k) * HH + c) * LL + j0 + jjl) * DD + a];
            }
            __syncthreads();
            for (int jj = 0; jj < 64; ++jj) {
                int j = j0 + jj;
                float4 b4 = LD4(sB, jj, tx * 4);
#pragma unroll
                for (int q = 0; q < 4; ++q) {
                    float wq = sQh[ty * 4 + q][jj] * wt[tdx(ibase + q - j)][k];
                    acc[q][0] += wq * b4.x; acc[q][1] += wq * b4.y;
                    acc[q][2] += wq * b4.z; acc[q][3] += wq * b4.w;
                }
            }
        }
    }
    int slot = c * 4 + jc;          // 0..31
#pragma unroll
    for (int q = 0; q < 4; ++q)
        *reinterpret_cast<float4*>(&PG[(((size_t)slot * BB + z) * LL + ibase + q) * DD + tx * 4]) =
            make_float4(acc[q][0], acc[q][1], acc[q][2], acc[q][3]);
}

// ---------------- K6: g2 partials. g2[i,a] = sum_{k,c,j} Qh[c,j,i] dm_k(j-i) M2N[k,c,j,a] ----------------
__global__ void k_g2(const float* __restrict__ SH, const float* __restrict__ M2N,
                     const float* __restrict__ dp, float* __restrict__ PG) {
    int it = blockIdx.x;
    int jc = blockIdx.y;
    int z = blockIdx.z >> 3, c = blockIdx.z & 7;
    __shared__ __align__(16) float sQh[64][68];   // [jj][ii]  (transposed access)
    __shared__ __align__(16) float sB[64][68];    // [jj][a]
    __shared__ float wt[9][4];
    int tid = threadIdx.x;
    if (tid < 36) { int t = tid >> 2, kk = tid & 3; wt[t][kk] = (t == 0) ? 0.f : dp[(t - 1) * 4 + kk]; }
    int ty = tid >> 4, tx = tid & 15;
    int ibase = it * 64 + ty * 4;
    float acc[4][4] = {};
    for (int js = 0; js < 2; ++js) {
        int j0 = jc * 128 + js * 64;
        __syncthreads();
        for (int idx = tid; idx < 4096; idx += 256) {
            int jjl = idx >> 6, ii = idx & 63;
            sQh[jjl][ii] = SH[(((size_t)z * HH + c) * LL + j0 + jjl) * LL + it * 64 + ii];
        }
        for (int k = 0; k < KK; ++k) {
            __syncthreads();
            for (int idx = tid; idx < 4096; idx += 256) {
                int jjl = idx >> 6, a = idx & 63;
                sB[jjl][a] = M2N[((((size_t)z * KK + k) * HH + c) * LL + j0 + jjl) * DD + a];
            }
            __syncthreads();
            for (int jj = 0; jj < 64; ++jj) {
                int j = j0 + jj;
                float4 b4 = LD4(sB, jj, tx * 4);
#pragma unroll
                for (int q = 0; q < 4; ++q) {
                    float wq = sQh[jj][ty * 4 + q] * wt[tdx(j - (ibase + q))][k];
                    acc[q][0] += wq * b4.x; acc[q][1] += wq * b4.y;
                    acc[q][2] += wq * b4.z; acc[q][3] += wq * b4.w;
                }
            }
        }
    }
    int slot = 32 + c * 4 + jc;     // 32..63
#pragma unroll
    for (int q = 0; q < 4; ++q)
        *reinterpret_cast<float4*>(&PG[(((size_t)slot * BB + z) * LL + ibase + q) * DD + tx * 4]) =
            make_float4(acc[q][0], acc[q][1], acc[q][2], acc[q][3]);
}

// ---------------- K7: q_next = x + sum(64 partial slots) + gg ----------------
__global__ void k_update(const float* __restrict__ x, const float* __restrict__ PG,
                         const float* __restrict__ QG, const float* __restrict__ gp,
                         float* __restrict__ outq) {
    __shared__ __align__(16) float gpS[64][68];   // [g][a]
    int tid = threadIdx.x;
    for (int idx = tid; idx < 4096; idx += 256) gpS[idx >> 6][idx & 63] = gp[idx];
    __syncthreads();
    int row = blockIdx.x * 4 + (tid >> 6);        // B*L
    int a = tid & 63;
    float acc = x[row * DD + a];
    float qgv = QG[row * GG + a];
    for (int g = 0; g < 64; ++g) acc += __shfl(qgv, g, 64) * gpS[g][a];
    for (int s = 0; s < 64; ++s) acc += PG[((size_t)s * BB * LL + row) * DD + a];
    outq[row * DD + a] = acc;
}

extern "C" void kernel_launch(void* const* d_in, const int* in_sizes, int n_in,
                              void* d_out, int out_size, void* d_ws, size_t ws_size,
                              hipStream_t stream) {
    const float* x    = (const float*)d_in[0];
    const int*   mask = (const int*)d_in[1];
    const float* dp   = (const float*)d_in[2];
    const float* T    = (const float*)d_in[3];
    const float* gp   = (const float*)d_in[4];
    float* out = (float*)d_out;
    float* ws  = (float*)d_ws;

    const size_t nQZ = (size_t)BB * LL * DD;            // 65536
    const size_t nM  = (size_t)BB * KK * HH * LL * DD;  // 2097152
    const size_t nSH = (size_t)BB * HH * LL * LL;       // 4194304
    const size_t nQG = (size_t)BB * LL * GG;            // 65536
    const size_t nPG = (size_t)64 * BB * LL * DD;       // 4194304

    float* Qz  = ws;
    float* M1T = Qz + nQZ;
    float* M1N = M1T + nM;
    float* M2N = M1N + nM;
    float* SH  = M2N + nM;
    float* QG  = SH + nSH;
    float* PG  = QG + nQG;
    float* QZ1 = PG + nPG;
    // total ws use: ~59.5 MB (floats)

    const float* qsrc = x;
    for (int iter = 0; iter < 2; ++iter) {
        float* qdst = (iter == 0) ? QZ1 : out;
        hipLaunchKernelGGL(k_softmax_qz, dim3(256), dim3(256), 0, stream, qsrc, Qz);
        hipLaunchKernelGGL(k_compute_M, dim3(8, 8, 8), dim3(256), 0, stream, Qz, T, M1T, M1N, M2N);
        hipLaunchKernelGGL(k_sh, dim3(8, 8, 16), dim3(256), 0, stream, Qz, M1T, dp, mask, SH);
        hipLaunchKernelGGL(k_softmax_sh, dim3(2048), dim3(256), 0, stream, SH);
        hipLaunchKernelGGL(k_qg, dim3(256), dim3(256), 0, stream, Qz, gp, mask, QG);
        hipLaunchKernelGGL(k_g1, dim3(8, 4, 16), dim3(256), 0, stream, SH, M1N, dp, PG);
        hipLaunchKernelGGL(k_g2, dim3(8, 4, 16), dim3(256), 0, stream, SH, M2N, dp, PG);
        hipLaunchKernelGGL(k_update, dim3(256), dim3(256), 0, stream, x, PG, QG, gp, qdst);
        qsrc = qdst;
    }
}

// Round 2
// 1269.278 us; speedup vs baseline: 1.1131x; 1.1131x over previous
//
#include <hip/hip_runtime.h>

#define BB 2
#define LL 512
#define DD 64
#define HH 8
#define GG 64
#define KK 4
#define NEGV -1e9f

// distance-table index for delta = i - j (clip to [-4,4], torch negative wrap)
__device__ __forceinline__ int tdx(int delta) {
    delta = delta < -4 ? -4 : (delta > 4 ? 4 : delta);
    return delta < 0 ? delta + 9 : delta;
}

#define LD4(arr, r, c_) (*reinterpret_cast<const float4*>(&(arr)[r][c_]))

// ---------------- K1: Q_z = softmax(q_z) over d=64; one wave per row ----------------
__global__ __launch_bounds__(256) void k_softmax_qz(const float* __restrict__ src, float* __restrict__ Qz) {
    int row = blockIdx.x * 4 + (threadIdx.x >> 6);   // B*L = 1024 rows
    int lane = threadIdx.x & 63;
    float v = src[row * DD + lane];
    float m = v;
#pragma unroll
    for (int o = 32; o > 0; o >>= 1) m = fmaxf(m, __shfl_xor(m, o, 64));
    float e = __expf(v - m);
    float s = e;
#pragma unroll
    for (int o = 32; o > 0; o >>= 1) s += __shfl_xor(s, o, 64);
    Qz[row * DD + lane] = e / s;
}

// ---------------- K2: M1/M2 tensor messages ----------------
// M1[z,k,j,a,c] = sum_b Qz[z,j,b] T[k,a,b,c];  M2 swaps a/b roles.
// Stores: M1N [z,k,c,j,a], M2N [z,k,c,j,a], M1T [z,k,c,a,j]
__global__ __launch_bounds__(256, 3) void k_compute_M(const float* __restrict__ Qz, const float* __restrict__ T,
                            float* __restrict__ M1T, float* __restrict__ M1N,
                            float* __restrict__ M2N) {
    int jt = blockIdx.x;            // 8 j-tiles of 64
    int c  = blockIdx.y;            // 8
    int z  = blockIdx.z >> 2;       // 2
    int k  = blockIdx.z & 3;        // 4
    __shared__ __align__(16) float sQ[64][68];
    __shared__ __align__(16) float sT1[64][68];   // [b][a] = T[k,a,b,c]
    __shared__ __align__(16) float sT2[64][68];   // [b][a] = T[k,b,a,c]
    int tid = threadIdx.x;
    for (int idx = tid; idx < 4096; idx += 256) {
        int a = idx >> 6, b = idx & 63;
        sT1[b][a] = T[(((k * 64 + a) * 64 + b) << 3) + c];
        sT2[b][a] = T[(((k * 64 + b) * 64 + a) << 3) + c];
        sQ[a][b]  = Qz[(z * LL + jt * 64 + a) * DD + b];   // a reused as jj here
    }
    __syncthreads();
    int jj = tid >> 2;
    int a0 = (tid & 3) << 4;
    float m1[16], m2[16];
#pragma unroll
    for (int r = 0; r < 16; ++r) { m1[r] = 0.f; m2[r] = 0.f; }
    for (int b = 0; b < 64; ++b) {
        float q = sQ[jj][b];
#pragma unroll
        for (int u = 0; u < 4; ++u) {
            float4 t1 = LD4(sT1, b, a0 + u * 4);
            float4 t2 = LD4(sT2, b, a0 + u * 4);
            m1[u*4+0] += q * t1.x; m1[u*4+1] += q * t1.y; m1[u*4+2] += q * t1.z; m1[u*4+3] += q * t1.w;
            m2[u*4+0] += q * t2.x; m2[u*4+1] += q * t2.y; m2[u*4+2] += q * t2.z; m2[u*4+3] += q * t2.w;
        }
    }
    int j = jt * 64 + jj;
    size_t base = ((((size_t)z * KK + k) * HH + c) * LL + j) * DD + a0;
#pragma unroll
    for (int u = 0; u < 4; ++u) {
        *reinterpret_cast<float4*>(&M1N[base + u * 4]) =
            make_float4(m1[u*4+0], m1[u*4+1], m1[u*4+2], m1[u*4+3]);
        *reinterpret_cast<float4*>(&M2N[base + u * 4]) =
            make_float4(m2[u*4+0], m2[u*4+1], m2[u*4+2], m2[u*4+3]);
    }
    size_t baseT = ((((size_t)z * KK + k) * HH + c) * DD + a0) * LL + j;
#pragma unroll
    for (int r = 0; r < 16; ++r) M1T[baseT + (size_t)r * LL] = m1[r];
}

// ---------------- K3a: s_h[z,c,i,j] = sum_k dm_k(i-j) * (Qz[i,:] . M1T[k,c,:,j]) + mask ----------------
__global__ __launch_bounds__(256, 4) void k_sh(const float* __restrict__ Qz, const float* __restrict__ M1T,
                     const float* __restrict__ dp, const int* __restrict__ mask,
                     float* __restrict__ SH) {
    int jt = blockIdx.x, it = blockIdx.y;
    int z = blockIdx.z >> 3, c = blockIdx.z & 7;
    __shared__ __align__(16) float sA[64][68];   // [ii][a]
    __shared__ __align__(16) float sB[64][68];   // [a][jj]
    __shared__ float wt[9][4];
    __shared__ int mrow[64], mcol[64];
    int tid = threadIdx.x;
    if (tid < 36) { int t = tid >> 2, kk = tid & 3; wt[t][kk] = (t == 0) ? 0.f : dp[(t - 1) * 4 + kk]; }
    if (tid >= 64 && tid < 128)  mrow[tid - 64]  = mask[z * LL + it * 64 + (tid - 64)];
    if (tid >= 128 && tid < 192) mcol[tid - 128] = mask[z * LL + jt * 64 + (tid - 128)];
    for (int idx = tid; idx < 4096; idx += 256) {
        int ii = idx >> 6, a = idx & 63;
        sA[ii][a] = Qz[(z * LL + it * 64 + ii) * DD + a];
    }
    int ty = tid >> 4, tx = tid & 15;
    float acc[4][4] = {};
    for (int k = 0; k < KK; ++k) {
        __syncthreads();
        size_t bbase = ((((size_t)z * KK + k) * HH + c) * DD) * LL + jt * 64;
        for (int idx = tid; idx < 4096; idx += 256) {
            int a = idx >> 6, jjl = idx & 63;
            sB[a][jjl] = M1T[bbase + (size_t)a * LL + jjl];
        }
        __syncthreads();
        float tmp[4][4] = {};
        for (int a4 = 0; a4 < 64; a4 += 4) {
            float bvv[4][4];
#pragma unroll
            for (int u = 0; u < 4; ++u) {
                float4 b4 = LD4(sB, a4 + u, tx * 4);
                bvv[u][0] = b4.x; bvv[u][1] = b4.y; bvv[u][2] = b4.z; bvv[u][3] = b4.w;
            }
#pragma unroll
            for (int q = 0; q < 4; ++q) {
                float4 a4v = LD4(sA, ty * 4 + q, a4);
#pragma unroll
                for (int r = 0; r < 4; ++r)
                    tmp[q][r] += a4v.x * bvv[0][r] + a4v.y * bvv[1][r]
                               + a4v.z * bvv[2][r] + a4v.w * bvv[3][r];
            }
        }
#pragma unroll
        for (int q = 0; q < 4; ++q) {
            int i = it * 64 + ty * 4 + q;
#pragma unroll
            for (int r = 0; r < 4; ++r) {
                int j = jt * 64 + tx * 4 + r;
                acc[q][r] += wt[tdx(i - j)][k] * tmp[q][r];
            }
        }
    }
#pragma unroll
    for (int q = 0; q < 4; ++q) {
        int i = it * 64 + ty * 4 + q;
        float vals[4];
#pragma unroll
        for (int r = 0; r < 4; ++r)
            vals[r] = (mrow[ty * 4 + q] && mcol[tx * 4 + r]) ? acc[q][r] : NEGV;
        *reinterpret_cast<float4*>(&SH[(((size_t)z * HH + c) * LL + i) * LL + jt * 64 + tx * 4]) =
            make_float4(vals[0], vals[1], vals[2], vals[3]);
    }
}

// ---------------- K3b: Q_h = softmax over j (512); one wave per row, in place ----------------
__global__ __launch_bounds__(256) void k_softmax_sh(float* __restrict__ SH) {
    int row = blockIdx.x * 4 + (threadIdx.x >> 6);   // B*H*L = 8192 rows
    int lane = threadIdx.x & 63;
    float v[8];
    float m = -1e30f;
#pragma unroll
    for (int r = 0; r < 8; ++r) { v[r] = SH[(size_t)row * LL + r * 64 + lane]; m = fmaxf(m, v[r]); }
#pragma unroll
    for (int o = 32; o > 0; o >>= 1) m = fmaxf(m, __shfl_xor(m, o, 64));
    float s = 0.f;
#pragma unroll
    for (int r = 0; r < 8; ++r) { v[r] = __expf(v[r] - m); s += v[r]; }
#pragma unroll
    for (int o = 32; o > 0; o >>= 1) s += __shfl_xor(s, o, 64);
    float inv = 1.f / s;
#pragma unroll
    for (int r = 0; r < 8; ++r) SH[(size_t)row * LL + r * 64 + lane] = v[r] * inv;
}

// ---------------- K4: Q_g = softmax_g( Qz . gp^T ), one wave per (z,i) ----------------
__global__ __launch_bounds__(256) void k_qg(const float* __restrict__ Qz, const float* __restrict__ gp,
                     const int* __restrict__ mask, float* __restrict__ QG) {
    __shared__ __align__(16) float gpS[64][68];   // [g][a]
    int tid = threadIdx.x;
    for (int idx = tid; idx < 4096; idx += 256) gpS[idx >> 6][idx & 63] = gp[idx];
    __syncthreads();
    int row = blockIdx.x * 4 + (tid >> 6);        // B*L
    int g = tid & 63;
    float qv = Qz[row * DD + g];
    float s = 0.f;
    for (int a = 0; a < 64; ++a) s += __shfl(qv, a, 64) * gpS[g][a];
    if (mask[row] == 0) s = NEGV;
    float m = s;
#pragma unroll
    for (int o = 32; o > 0; o >>= 1) m = fmaxf(m, __shfl_xor(m, o, 64));
    float e = __expf(s - m);
    float sum = e;
#pragma unroll
    for (int o = 32; o > 0; o >>= 1) sum += __shfl_xor(sum, o, 64);
    QG[row * GG + g] = e / sum;
}

// ---------------- K5: g1 partials. g1[i,a] = sum_{k,c,j} Qh[c,i,j] dm_k(i-j) M1N[k,c,j,a] ----------------
__global__ __launch_bounds__(256, 4) void k_g1(const float* __restrict__ SH, const float* __restrict__ M1N,
                     const float* __restrict__ dp, float* __restrict__ PG) {
    int it = blockIdx.x;            // 8 i-tiles
    int jc = blockIdx.y;            // 4 j-chunks of 128
    int z = blockIdx.z >> 3, c = blockIdx.z & 7;
    __shared__ __align__(16) float sQh[64][68];   // [ii][jj]
    __shared__ __align__(16) float sB[64][68];    // [jj][a]
    __shared__ float wt[9][4];
    int tid = threadIdx.x;
    if (tid < 36) { int t = tid >> 2, kk = tid & 3; wt[t][kk] = (t == 0) ? 0.f : dp[(t - 1) * 4 + kk]; }
    int ty = tid >> 4, tx = tid & 15;
    int ibase = it * 64 + ty * 4;
    float acc[4][4] = {};
    for (int js = 0; js < 2; ++js) {
        int j0 = jc * 128 + js * 64;
        __syncthreads();
        for (int idx = tid; idx < 4096; idx += 256) {
            int ii = idx >> 6, jjl = idx & 63;
            sQh[ii][jjl] = SH[(((size_t)z * HH + c) * LL + it * 64 + ii) * LL + j0 + jjl];
        }
        for (int k = 0; k < KK; ++k) {
            __syncthreads();
            for (int idx = tid; idx < 4096; idx += 256) {
                int jjl = idx >> 6, a = idx & 63;
                sB[jjl][a] = M1N[((((size_t)z * KK + k) * HH + c) * LL + j0 + jjl) * DD + a];
            }
            __syncthreads();
            for (int jj = 0; jj < 64; ++jj) {
                int j = j0 + jj;
                float4 b4 = LD4(sB, jj, tx * 4);
#pragma unroll
                for (int q = 0; q < 4; ++q) {
                    float wq = sQh[ty * 4 + q][jj] * wt[tdx(ibase + q - j)][k];
                    acc[q][0] += wq * b4.x; acc[q][1] += wq * b4.y;
                    acc[q][2] += wq * b4.z; acc[q][3] += wq * b4.w;
                }
            }
        }
    }
    int slot = c * 4 + jc;          // 0..31
#pragma unroll
    for (int q = 0; q < 4; ++q)
        *reinterpret_cast<float4*>(&PG[(((size_t)slot * BB + z) * LL + ibase + q) * DD + tx * 4]) =
            make_float4(acc[q][0], acc[q][1], acc[q][2], acc[q][3]);
}

// ---------------- K6: g2 partials. g2[i,a] = sum_{k,c,j} Qh[c,j,i] dm_k(j-i) M2N[k,c,j,a] ----------------
__global__ __launch_bounds__(256, 4) void k_g2(const float* __restrict__ SH, const float* __restrict__ M2N,
                     const float* __restrict__ dp, float* __restrict__ PG) {
    int it = blockIdx.x;
    int jc = blockIdx.y;
    int z = blockIdx.z >> 3, c = blockIdx.z & 7;
    __shared__ __align__(16) float sQh[64][68];   // [jj][ii]  (transposed access)
    __shared__ __align__(16) float sB[64][68];    // [jj][a]
    __shared__ float wt[9][4];
    int tid = threadIdx.x;
    if (tid < 36) { int t = tid >> 2, kk = tid & 3; wt[t][kk] = (t == 0) ? 0.f : dp[(t - 1) * 4 + kk]; }
    int ty = tid >> 4, tx = tid & 15;
    int ibase = it * 64 + ty * 4;
    float acc[4][4] = {};
    for (int js = 0; js < 2; ++js) {
        int j0 = jc * 128 + js * 64;
        __syncthreads();
        for (int idx = tid; idx < 4096; idx += 256) {
            int jjl = idx >> 6, ii = idx & 63;
            sQh[jjl][ii] = SH[(((size_t)z * HH + c) * LL + j0 + jjl) * LL + it * 64 + ii];
        }
        for (int k = 0; k < KK; ++k) {
            __syncthreads();
            for (int idx = tid; idx < 4096; idx += 256) {
                int jjl = idx >> 6, a = idx & 63;
                sB[jjl][a] = M2N[((((size_t)z * KK + k) * HH + c) * LL + j0 + jjl) * DD + a];
            }
            __syncthreads();
            for (int jj = 0; jj < 64; ++jj) {
                int j = j0 + jj;
                float4 b4 = LD4(sB, jj, tx * 4);
#pragma unroll
                for (int q = 0; q < 4; ++q) {
                    float wq = sQh[jj][ty * 4 + q] * wt[tdx(j - (ibase + q))][k];
                    acc[q][0] += wq * b4.x; acc[q][1] += wq * b4.y;
                    acc[q][2] += wq * b4.z; acc[q][3] += wq * b4.w;
                }
            }
        }
    }
    int slot = 32 + c * 4 + jc;     // 32..63
#pragma unroll
    for (int q = 0; q < 4; ++q)
        *reinterpret_cast<float4*>(&PG[(((size_t)slot * BB + z) * LL + ibase + q) * DD + tx * 4]) =
            make_float4(acc[q][0], acc[q][1], acc[q][2], acc[q][3]);
}

// ---------------- K7: q_next = x + sum(64 partial slots) + gg ----------------
__global__ __launch_bounds__(256) void k_update(const float* __restrict__ x, const float* __restrict__ PG,
                         const float* __restrict__ QG, const float* __restrict__ gp,
                         float* __restrict__ outq) {
    __shared__ __align__(16) float gpS[64][68];   // [g][a]
    int tid = threadIdx.x;
    for (int idx = tid; idx < 4096; idx += 256) gpS[idx >> 6][idx & 63] = gp[idx];
    __syncthreads();
    int row = blockIdx.x * 4 + (tid >> 6);        // B*L
    int a = tid & 63;
    float acc = x[row * DD + a];
    float qgv = QG[row * GG + a];
    for (int g = 0; g < 64; ++g) acc += __shfl(qgv, g, 64) * gpS[g][a];
    for (int s = 0; s < 64; ++s) acc += PG[((size_t)s * BB * LL + row) * DD + a];
    outq[row * DD + a] = acc;
}

extern "C" void kernel_launch(void* const* d_in, const int* in_sizes, int n_in,
                              void* d_out, int out_size, void* d_ws, size_t ws_size,
                              hipStream_t stream) {
    const float* x    = (const float*)d_in[0];
    const int*   mask = (const int*)d_in[1];
    const float* dp   = (const float*)d_in[2];
    const float* T    = (const float*)d_in[3];
    const float* gp   = (const float*)d_in[4];
    float* out = (float*)d_out;
    float* ws  = (float*)d_ws;

    const size_t nQZ = (size_t)BB * LL * DD;            // 65536
    const size_t nM  = (size_t)BB * KK * HH * LL * DD;  // 2097152
    const size_t nSH = (size_t)BB * HH * LL * LL;       // 4194304
    const size_t nQG = (size_t)BB * LL * GG;            // 65536
    const size_t nPG = (size_t)64 * BB * LL * DD;       // 4194304

    float* Qz  = ws;
    float* M1T = Qz + nQZ;
    float* M1N = M1T + nM;
    float* M2N = M1N + nM;
    float* SH  = M2N + nM;
    float* QG  = SH + nSH;
    float* PG  = QG + nQG;
    float* QZ1 = PG + nPG;
    // total ws use: ~59.5 MB (floats)

    const float* qsrc = x;
    for (int iter = 0; iter < 2; ++iter) {
        float* qdst = (iter == 0) ? QZ1 : out;
        hipLaunchKernelGGL(k_softmax_qz, dim3(256), dim3(256), 0, stream, qsrc, Qz);
        hipLaunchKernelGGL(k_compute_M, dim3(8, 8, 8), dim3(256), 0, stream, Qz, T, M1T, M1N, M2N);
        hipLaunchKernelGGL(k_sh, dim3(8, 8, 16), dim3(256), 0, stream, Qz, M1T, dp, mask, SH);
        hipLaunchKernelGGL(k_softmax_sh, dim3(2048), dim3(256), 0, stream, SH);
        hipLaunchKernelGGL(k_qg, dim3(256), dim3(256), 0, stream, Qz, gp, mask, QG);
        hipLaunchKernelGGL(k_g1, dim3(8, 4, 16), dim3(256), 0, stream, SH, M1N, dp, PG);
        hipLaunchKernelGGL(k_g2, dim3(8, 4, 16), dim3(256), 0, stream, SH, M2N, dp, PG);
        hipLaunchKernelGGL(k_update, dim3(256), dim3(256), 0, stream, x, PG, QG, gp, qdst);
        qsrc = qdst;
    }
}

// Round 3
// 382.363 us; speedup vs baseline: 3.6949x; 3.3196x over previous
//
#include <hip/hip_runtime.h>

#define BB 2
#define LL 512
#define DD 64
#define HH 8
#define GG 64
#define KK 4
#define NEGV -1e9f
#define NSLOT 68

#define LD4(arr, r, c_) (*reinterpret_cast<const float4*>(&(arr)[r][c_]))

// ---------------- K1: Q_z = softmax(q_z) over d=64; one wave per row ----------------
__global__ __launch_bounds__(256) void k_softmax_qz(const float* __restrict__ src, float* __restrict__ Qz) {
    int row = blockIdx.x * 4 + (threadIdx.x >> 6);   // B*L = 1024 rows
    int lane = threadIdx.x & 63;
    float v = src[row * DD + lane];
    float m = v;
#pragma unroll
    for (int o = 32; o > 0; o >>= 1) m = fmaxf(m, __shfl_xor(m, o, 64));
    float e = __expf(v - m);
    float s = e;
#pragma unroll
    for (int o = 32; o > 0; o >>= 1) s += __shfl_xor(s, o, 64);
    Qz[row * DD + lane] = e / s;
}

// ---------------- K2: M1/M2 tensor messages ----------------
// M1N[z,k,c,j,a] = sum_b Qz[z,j,b] T[k,a,b,c];  M2N[z,k,c,j,a] = sum_b Qz[z,j,b] T[k,b,a,c]
__global__ __launch_bounds__(256, 3) void k_compute_M(const float* __restrict__ Qz, const float* __restrict__ T,
                            float* __restrict__ M1N, float* __restrict__ M2N) {
    int jt = blockIdx.x;            // 8 j-tiles of 64
    int c  = blockIdx.y;            // 8
    int z  = blockIdx.z >> 2;       // 2
    int k  = blockIdx.z & 3;        // 4
    __shared__ __align__(16) float sQ[64][68];
    __shared__ __align__(16) float sT1[64][68];   // [b][a] = T[k,a,b,c]
    __shared__ __align__(16) float sT2[64][68];   // [b][a] = T[k,b,a,c]
    int tid = threadIdx.x;
    for (int idx = tid; idx < 4096; idx += 256) {
        int a = idx >> 6, b = idx & 63;
        sT1[b][a] = T[(((k * 64 + a) * 64 + b) << 3) + c];
        sT2[b][a] = T[(((k * 64 + b) * 64 + a) << 3) + c];
        sQ[a][b]  = Qz[(z * LL + jt * 64 + a) * DD + b];   // a reused as jj here
    }
    __syncthreads();
    int jj = tid >> 2;
    int a0 = (tid & 3) << 4;
    float m1[16], m2[16];
#pragma unroll
    for (int r = 0; r < 16; ++r) { m1[r] = 0.f; m2[r] = 0.f; }
    for (int b = 0; b < 64; ++b) {
        float q = sQ[jj][b];
#pragma unroll
        for (int u = 0; u < 4; ++u) {
            float4 t1 = LD4(sT1, b, a0 + u * 4);
            float4 t2 = LD4(sT2, b, a0 + u * 4);
            m1[u*4+0] += q * t1.x; m1[u*4+1] += q * t1.y; m1[u*4+2] += q * t1.z; m1[u*4+3] += q * t1.w;
            m2[u*4+0] += q * t2.x; m2[u*4+1] += q * t2.y; m2[u*4+2] += q * t2.z; m2[u*4+3] += q * t2.w;
        }
    }
    int j = jt * 64 + jj;
    size_t base = ((((size_t)z * KK + k) * HH + c) * LL + j) * DD + a0;
#pragma unroll
    for (int u = 0; u < 4; ++u) {
        *reinterpret_cast<float4*>(&M1N[base + u * 4]) =
            make_float4(m1[u*4+0], m1[u*4+1], m1[u*4+2], m1[u*4+3]);
        *reinterpret_cast<float4*>(&M2N[base + u * 4]) =
            make_float4(m2[u*4+0], m2[u*4+1], m2[u*4+2], m2[u*4+3]);
    }
}

// ---------------- K2b: collapse k with far-field weights ----------------
// MPN = sum_k wt[4][k]*M1N ; MMN = sum_k wt[5][k]*M1N ; MP2N/MM2N same from M2N. Layout [z,c,j,a].
__global__ __launch_bounds__(256) void k_collapse(const float* __restrict__ M1N, const float* __restrict__ M2N,
                                                  const float* __restrict__ dp,
                                                  float* __restrict__ MPN, float* __restrict__ MMN,
                                                  float* __restrict__ MP2N, float* __restrict__ MM2N) {
    int idx = blockIdx.x * 256 + threadIdx.x;      // 131072 float4 outputs
    int a  = (idx & 15) * 4;
    int j  = (idx >> 4) & 511;
    int c  = (idx >> 13) & 7;
    int z  = (idx >> 16) & 1;
    float w4[4], w5[4];
#pragma unroll
    for (int k = 0; k < 4; ++k) { w4[k] = dp[12 + k]; w5[k] = dp[16 + k]; }
    float4 p1 = make_float4(0,0,0,0), m1 = make_float4(0,0,0,0);
    float4 p2 = make_float4(0,0,0,0), m2 = make_float4(0,0,0,0);
#pragma unroll
    for (int k = 0; k < 4; ++k) {
        size_t off = ((((size_t)z * KK + k) * HH + c) * LL + j) * DD + a;
        float4 v1 = *reinterpret_cast<const float4*>(&M1N[off]);
        float4 v2 = *reinterpret_cast<const float4*>(&M2N[off]);
        p1.x += w4[k]*v1.x; p1.y += w4[k]*v1.y; p1.z += w4[k]*v1.z; p1.w += w4[k]*v1.w;
        m1.x += w5[k]*v1.x; m1.y += w5[k]*v1.y; m1.z += w5[k]*v1.z; m1.w += w5[k]*v1.w;
        p2.x += w4[k]*v2.x; p2.y += w4[k]*v2.y; p2.z += w4[k]*v2.z; p2.w += w4[k]*v2.w;
        m2.x += w5[k]*v2.x; m2.y += w5[k]*v2.y; m2.z += w5[k]*v2.z; m2.w += w5[k]*v2.w;
    }
    size_t o = (((size_t)z * HH + c) * LL + j) * DD + a;
    *reinterpret_cast<float4*>(&MPN[o])  = p1;
    *reinterpret_cast<float4*>(&MMN[o])  = m1;
    *reinterpret_cast<float4*>(&MP2N[o]) = p2;
    *reinterpret_cast<float4*>(&MM2N[o]) = m2;
}

// ---------------- K2c: exact s_h values on the 7-diagonal band ----------------
// BAND[z,c,j,d+3] = sum_a Qz[j+d,a] * (sum_k wt[tdx(d)][k] * M1N[k,c,j,a]),  d = i-j in [-3,3]
__global__ __launch_bounds__(256) void k_band(const float* __restrict__ Qz, const float* __restrict__ M1N,
                                              const float* __restrict__ dp, float* __restrict__ BAND) {
    int w = blockIdx.x * 4 + (threadIdx.x >> 6);   // 8192 waves: (z,c,j)
    int lane = threadIdx.x & 63;
    int j = w & 511, c = (w >> 9) & 7, z = w >> 12;
    float m[4];
#pragma unroll
    for (int k = 0; k < 4; ++k)
        m[k] = M1N[((((size_t)z * KK + k) * HH + c) * LL + j) * DD + lane];
    float out = 0.f;
#pragma unroll
    for (int d = -3; d <= 3; ++d) {
        int i = j + d;
        if (i < 0 || i >= LL) continue;
        int idx = d < 0 ? d + 9 : d;
        float t = 0.f;
        if (idx != 0) {
#pragma unroll
            for (int k = 0; k < 4; ++k) t += dp[(idx - 1) * 4 + k] * m[k];
        }
        float s = Qz[(z * LL + i) * DD + lane] * t;
#pragma unroll
        for (int o = 32; o > 0; o >>= 1) s += __shfl_xor(s, o, 64);
        if (lane == d + 3) out = s;
    }
    if (lane < 7) BAND[(size_t)w * 8 + lane] = out;
}

#define GEMM_ACC(ACC) \
        for (int a4 = 0; a4 < 64; a4 += 4) { \
            float bvv[4][4]; \
            _Pragma("unroll") \
            for (int u = 0; u < 4; ++u) { \
                float4 b4 = LD4(sB, a4 + u, tx * 4); \
                bvv[u][0] = b4.x; bvv[u][1] = b4.y; bvv[u][2] = b4.z; bvv[u][3] = b4.w; } \
            _Pragma("unroll") \
            for (int q = 0; q < 4; ++q) { \
                float4 a4v = LD4(sA, ty * 4 + q, a4); \
                _Pragma("unroll") \
                for (int r = 0; r < 4; ++r) \
                    ACC[q][r] += a4v.x * bvv[0][r] + a4v.y * bvv[1][r] \
                               + a4v.z * bvv[2][r] + a4v.w * bvv[3][r]; } \
        }

// ---------------- K3a: s_h main GEMM + band overwrite + mask ----------------
__global__ __launch_bounds__(256, 4) void k_sh(const float* __restrict__ Qz,
                     const float* __restrict__ MPN, const float* __restrict__ MMN,
                     const float* __restrict__ BAND, const int* __restrict__ mask,
                     float* __restrict__ SH) {
    int jt = blockIdx.x, it = blockIdx.y;
    int z = blockIdx.z >> 3, c = blockIdx.z & 7;
    __shared__ __align__(16) float sA[64][68];   // [ii][a]
    __shared__ __align__(16) float sB[64][68];   // [a][jj]  (transposed on load)
    __shared__ int mrow[64], mcol[64];
    int tid = threadIdx.x;
    if (tid < 64)       mrow[tid]      = mask[z * LL + it * 64 + tid];
    else if (tid < 128) mcol[tid - 64] = mask[z * LL + jt * 64 + (tid - 64)];
    for (int idx = tid; idx < 4096; idx += 256) {
        int ii = idx >> 6, a = idx & 63;
        sA[ii][a] = Qz[(z * LL + it * 64 + ii) * DD + a];
    }
    int ty = tid >> 4, tx = tid & 15;
    bool diag = (it == jt);
    int npass = diag ? 2 : 1;
    float accP[4][4] = {};
    float accM[4][4] = {};
    for (int pass = 0; pass < npass; ++pass) {
        const float* Bmat = (pass == 0) ? (diag ? MPN : (it > jt ? MPN : MMN)) : MMN;
        __syncthreads();
        for (int idx = tid; idx < 4096; idx += 256) {
            int jj = idx >> 6, a = idx & 63;
            sB[a][jj] = Bmat[(((size_t)z * HH + c) * LL + jt * 64 + jj) * DD + a];
        }
        __syncthreads();
        if (pass == 0) { GEMM_ACC(accP) } else { GEMM_ACC(accM) }
    }
#pragma unroll
    for (int q = 0; q < 4; ++q) {
        int i = it * 64 + ty * 4 + q;
        float vals[4];
#pragma unroll
        for (int r = 0; r < 4; ++r) {
            int j = jt * 64 + tx * 4 + r;
            float v = (diag && i <= j) ? accM[q][r] : accP[q][r];
            int d = i - j;
            if (d >= -3 && d <= 3)
                v = BAND[(((size_t)(z * HH + c) * LL + j)) * 8 + (d + 3)];
            vals[r] = (mrow[ty * 4 + q] && mcol[tx * 4 + r]) ? v : NEGV;
        }
        *reinterpret_cast<float4*>(&SH[(((size_t)z * HH + c) * LL + i) * LL + jt * 64 + tx * 4]) =
            make_float4(vals[0], vals[1], vals[2], vals[3]);
    }
}

// ---------------- K3b: Q_h = softmax over j (512); one wave per row, in place ----------------
__global__ __launch_bounds__(256) void k_softmax_sh(float* __restrict__ SH) {
    int row = blockIdx.x * 4 + (threadIdx.x >> 6);   // B*H*L = 8192 rows
    int lane = threadIdx.x & 63;
    float v[8];
    float m = -1e30f;
#pragma unroll
    for (int r = 0; r < 8; ++r) { v[r] = SH[(size_t)row * LL + r * 64 + lane]; m = fmaxf(m, v[r]); }
#pragma unroll
    for (int o = 32; o > 0; o >>= 1) m = fmaxf(m, __shfl_xor(m, o, 64));
    float s = 0.f;
#pragma unroll
    for (int r = 0; r < 8; ++r) { v[r] = __expf(v[r] - m); s += v[r]; }
#pragma unroll
    for (int o = 32; o > 0; o >>= 1) s += __shfl_xor(s, o, 64);
    float inv = 1.f / s;
#pragma unroll
    for (int r = 0; r < 8; ++r) SH[(size_t)row * LL + r * 64 + lane] = v[r] * inv;
}

// ---------------- K4: Q_g = softmax_g( Qz . gp^T ), one wave per (z,i) ----------------
__global__ __launch_bounds__(256) void k_qg(const float* __restrict__ Qz, const float* __restrict__ gp,
                     const int* __restrict__ mask, float* __restrict__ QG) {
    __shared__ __align__(16) float gpS[64][68];   // [g][a]
    int tid = threadIdx.x;
    for (int idx = tid; idx < 4096; idx += 256) gpS[idx >> 6][idx & 63] = gp[idx];
    __syncthreads();
    int row = blockIdx.x * 4 + (tid >> 6);        // B*L
    int g = tid & 63;
    float qv = Qz[row * DD + g];
    float s = 0.f;
    for (int a = 0; a < 64; ++a) s += __shfl(qv, a, 64) * gpS[g][a];
    if (mask[row] == 0) s = NEGV;
    float m = s;
#pragma unroll
    for (int o = 32; o > 0; o >>= 1) m = fmaxf(m, __shfl_xor(m, o, 64));
    float e = __expf(s - m);
    float sum = e;
#pragma unroll
    for (int o = 32; o > 0; o >>= 1) sum += __shfl_xor(sum, o, 64);
    QG[row * GG + g] = e / sum;
}

// ---------------- K5: g1 main GEMM. rule: i>j -> MPN, else MMN (band fixed by k_corr1) ----------------
__global__ __launch_bounds__(256, 4) void k_g1(const float* __restrict__ SH,
                     const float* __restrict__ MPN, const float* __restrict__ MMN,
                     float* __restrict__ PG) {
    int it = blockIdx.x, jc = blockIdx.y;
    int z = blockIdx.z >> 3, c = blockIdx.z & 7;
    __shared__ __align__(16) float sQh[64][68];   // [ii][jj]
    __shared__ __align__(16) float sB[64][68];    // [jj][a]
    int tid = threadIdx.x;
    int ty = tid >> 4, tx = tid & 15;
    int ibase = it * 64 + ty * 4;
    float acc[4][4] = {};
    for (int js = 0; js < 2; ++js) {
        int j0 = jc * 128 + js * 64;
        __syncthreads();
        for (int idx = tid; idx < 4096; idx += 256) {
            int ii = idx >> 6, jjl = idx & 63;
            sQh[ii][jjl] = SH[(((size_t)z * HH + c) * LL + it * 64 + ii) * LL + j0 + jjl];
        }
        bool dg = (j0 == it * 64);
        int npass = dg ? 2 : 1;
        for (int pass = 0; pass < npass; ++pass) {
            const float* Bmat = dg ? (pass == 0 ? MPN : MMN) : (j0 < it * 64 ? MPN : MMN);
            __syncthreads();
            for (int idx = tid; idx < 4096; idx += 256) {
                int jjl = idx >> 6, a = idx & 63;
                sB[jjl][a] = Bmat[(((size_t)z * HH + c) * LL + j0 + jjl) * DD + a];
            }
            __syncthreads();
            for (int jj = 0; jj < 64; ++jj) {
                int j = j0 + jj;
                float4 b4 = LD4(sB, jj, tx * 4);
#pragma unroll
                for (int q = 0; q < 4; ++q) {
                    int i = ibase + q;
                    float qh = sQh[ty * 4 + q][jj];
                    float w = dg ? (((pass == 0) == (i > j)) ? qh : 0.f) : qh;
                    acc[q][0] += w * b4.x; acc[q][1] += w * b4.y;
                    acc[q][2] += w * b4.z; acc[q][3] += w * b4.w;
                }
            }
        }
    }
    int slot = c * 4 + jc;          // 0..31
#pragma unroll
    for (int q = 0; q < 4; ++q)
        *reinterpret_cast<float4*>(&PG[(((size_t)slot * BB + z) * LL + ibase + q) * DD + tx * 4]) =
            make_float4(acc[q][0], acc[q][1], acc[q][2], acc[q][3]);
}

// ---------------- K6: g2 main GEMM. rule: j>i -> MP2N, else MM2N ----------------
__global__ __launch_bounds__(256, 4) void k_g2(const float* __restrict__ SH,
                     const float* __restrict__ MP2N, const float* __restrict__ MM2N,
                     float* __restrict__ PG) {
    int it = blockIdx.x, jc = blockIdx.y;
    int z = blockIdx.z >> 3, c = blockIdx.z & 7;
    __shared__ __align__(16) float sQh[64][68];   // [jj][ii]  (transposed access)
    __shared__ __align__(16) float sB[64][68];    // [jj][a]
    int tid = threadIdx.x;
    int ty = tid >> 4, tx = tid & 15;
    int ibase = it * 64 + ty * 4;
    float acc[4][4] = {};
    for (int js = 0; js < 2; ++js) {
        int j0 = jc * 128 + js * 64;
        __syncthreads();
        for (int idx = tid; idx < 4096; idx += 256) {
            int jjl = idx >> 6, ii = idx & 63;
            sQh[jjl][ii] = SH[(((size_t)z * HH + c) * LL + j0 + jjl) * LL + it * 64 + ii];
        }
        bool dg = (j0 == it * 64);
        int npass = dg ? 2 : 1;
        for (int pass = 0; pass < npass; ++pass) {
            const float* Bmat = dg ? (pass == 0 ? MP2N : MM2N) : (j0 > it * 64 ? MP2N : MM2N);
            __syncthreads();
            for (int idx = tid; idx < 4096; idx += 256) {
                int jjl = idx >> 6, a = idx & 63;
                sB[jjl][a] = Bmat[(((size_t)z * HH + c) * LL + j0 + jjl) * DD + a];
            }
            __syncthreads();
            for (int jj = 0; jj < 64; ++jj) {
                int j = j0 + jj;
                float4 b4 = LD4(sB, jj, tx * 4);
#pragma unroll
                for (int q = 0; q < 4; ++q) {
                    int i = ibase + q;
                    float qh = sQh[jj][ty * 4 + q];
                    float w = dg ? (((pass == 0) == (j > i)) ? qh : 0.f) : qh;
                    acc[q][0] += w * b4.x; acc[q][1] += w * b4.y;
                    acc[q][2] += w * b4.z; acc[q][3] += w * b4.w;
                }
            }
        }
    }
    int slot = 32 + c * 4 + jc;     // 32..63
#pragma unroll
    for (int q = 0; q < 4; ++q)
        *reinterpret_cast<float4*>(&PG[(((size_t)slot * BB + z) * LL + ibase + q) * DD + tx * 4]) =
            make_float4(acc[q][0], acc[q][1], acc[q][2], acc[q][3]);
}

// ---------------- K5b: band correction for g1: += Qh(c,i,j)*(exactW - mainW), j=i-d ----------------
__global__ __launch_bounds__(256) void k_corr1(const float* __restrict__ SH, const float* __restrict__ M1N,
                      const float* __restrict__ MPN, const float* __restrict__ MMN,
                      const float* __restrict__ dp, float* __restrict__ PG) {
    int w = blockIdx.x * 4 + (threadIdx.x >> 6);   // 2048 waves: (z,i,chalf)
    int lane = threadIdx.x & 63;
    int ch = w & 1, i = (w >> 1) & 511, z = w >> 10;
    float acc = 0.f;
    for (int cc = 0; cc < 4; ++cc) {
        int c = ch * 4 + cc;
#pragma unroll
        for (int d = -3; d <= 3; ++d) {
            int j = i - d;
            if (j < 0 || j >= LL) continue;
            float qh = SH[(((size_t)z * HH + c) * LL + i) * LL + j];
            int idx = d < 0 ? d + 9 : d;
            float e = 0.f;
            if (idx != 0) {
#pragma unroll
                for (int k = 0; k < 4; ++k)
                    e += dp[(idx - 1) * 4 + k] *
                         M1N[((((size_t)z * KK + k) * HH + c) * LL + j) * DD + lane];
            }
            const float* mainM = (d > 0) ? MPN : MMN;
            float mn = mainM[(((size_t)z * HH + c) * LL + j) * DD + lane];
            acc += qh * (e - mn);
        }
    }
    int slot = 64 + ch;
    PG[(((size_t)slot * BB + z) * LL + i) * DD + lane] = acc;
}

// ---------------- K6b: band correction for g2: += Qh(c,j,i)*(exactW2 - mainW2), j=i+d ----------------
__global__ __launch_bounds__(256) void k_corr2(const float* __restrict__ SH, const float* __restrict__ M2N,
                      const float* __restrict__ MP2N, const float* __restrict__ MM2N,
                      const float* __restrict__ dp, float* __restrict__ PG) {
    int w = blockIdx.x * 4 + (threadIdx.x >> 6);
    int lane = threadIdx.x & 63;
    int ch = w & 1, i = (w >> 1) & 511, z = w >> 10;
    float acc = 0.f;
    for (int cc = 0; cc < 4; ++cc) {
        int c = ch * 4 + cc;
#pragma unroll
        for (int d = -3; d <= 3; ++d) {
            int j = i + d;                         // d = j - i
            if (j < 0 || j >= LL) continue;
            float qh = SH[(((size_t)z * HH + c) * LL + j) * LL + i];
            int idx = d < 0 ? d + 9 : d;
            float e = 0.f;
            if (idx != 0) {
#pragma unroll
                for (int k = 0; k < 4; ++k)
                    e += dp[(idx - 1) * 4 + k] *
                         M2N[((((size_t)z * KK + k) * HH + c) * LL + j) * DD + lane];
            }
            const float* mainM = (d > 0) ? MP2N : MM2N;
            float mn = mainM[(((size_t)z * HH + c) * LL + j) * DD + lane];
            acc += qh * (e - mn);
        }
    }
    int slot = 66 + ch;
    PG[(((size_t)slot * BB + z) * LL + i) * DD + lane] = acc;
}

// ---------------- K7: q_next = x + sum(NSLOT partial slots) + gg ----------------
__global__ __launch_bounds__(256) void k_update(const float* __restrict__ x, const float* __restrict__ PG,
                         const float* __restrict__ QG, const float* __restrict__ gp,
                         float* __restrict__ outq) {
    __shared__ __align__(16) float gpS[64][68];   // [g][a]
    int tid = threadIdx.x;
    for (int idx = tid; idx < 4096; idx += 256) gpS[idx >> 6][idx & 63] = gp[idx];
    __syncthreads();
    int row = blockIdx.x * 4 + (tid >> 6);        // B*L
    int a = tid & 63;
    float acc = x[row * DD + a];
    float qgv = QG[row * GG + a];
    for (int g = 0; g < 64; ++g) acc += __shfl(qgv, g, 64) * gpS[g][a];
    for (int s = 0; s < NSLOT; ++s) acc += PG[((size_t)s * BB * LL + row) * DD + a];
    outq[row * DD + a] = acc;
}

extern "C" void kernel_launch(void* const* d_in, const int* in_sizes, int n_in,
                              void* d_out, int out_size, void* d_ws, size_t ws_size,
                              hipStream_t stream) {
    const float* x    = (const float*)d_in[0];
    const int*   mask = (const int*)d_in[1];
    const float* dp   = (const float*)d_in[2];
    const float* T    = (const float*)d_in[3];
    const float* gp   = (const float*)d_in[4];
    float* out = (float*)d_out;
    float* ws  = (float*)d_ws;

    const size_t nQZ = (size_t)BB * LL * DD;            // 65536
    const size_t nM  = (size_t)BB * KK * HH * LL * DD;  // 2097152
    const size_t nC  = (size_t)BB * HH * LL * DD;       // 524288
    const size_t nBD = (size_t)BB * HH * LL * 8;        // 65536
    const size_t nSH = (size_t)BB * HH * LL * LL;       // 4194304
    const size_t nQG = (size_t)BB * LL * GG;            // 65536
    const size_t nPG = (size_t)NSLOT * BB * LL * DD;    // 4456448

    float* Qz   = ws;
    float* M1N  = Qz + nQZ;
    float* M2N  = M1N + nM;
    float* MPN  = M2N + nM;
    float* MMN  = MPN + nC;
    float* MP2N = MMN + nC;
    float* MM2N = MP2N + nC;
    float* BAND = MM2N + nC;
    float* SH   = BAND + nBD;
    float* QG   = SH + nSH;
    float* PG   = QG + nQG;
    float* QZ1  = PG + nPG;
    // total ws use: ~61 MB

    const float* qsrc = x;
    for (int iter = 0; iter < 2; ++iter) {
        float* qdst = (iter == 0) ? QZ1 : out;
        hipLaunchKernelGGL(k_softmax_qz, dim3(256), dim3(256), 0, stream, qsrc, Qz);
        hipLaunchKernelGGL(k_compute_M, dim3(8, 8, 8), dim3(256), 0, stream, Qz, T, M1N, M2N);
        hipLaunchKernelGGL(k_collapse, dim3(512), dim3(256), 0, stream, M1N, M2N, dp, MPN, MMN, MP2N, MM2N);
        hipLaunchKernelGGL(k_band, dim3(2048), dim3(256), 0, stream, Qz, M1N, dp, BAND);
        hipLaunchKernelGGL(k_sh, dim3(8, 8, 16), dim3(256), 0, stream, Qz, MPN, MMN, BAND, mask, SH);
        hipLaunchKernelGGL(k_softmax_sh, dim3(2048), dim3(256), 0, stream, SH);
        hipLaunchKernelGGL(k_qg, dim3(256), dim3(256), 0, stream, Qz, gp, mask, QG);
        hipLaunchKernelGGL(k_g1, dim3(8, 4, 16), dim3(256), 0, stream, SH, MPN, MMN, PG);
        hipLaunchKernelGGL(k_g2, dim3(8, 4, 16), dim3(256), 0, stream, SH, MP2N, MM2N, PG);
        hipLaunchKernelGGL(k_corr1, dim3(512), dim3(256), 0, stream, SH, M1N, MPN, MMN, dp, PG);
        hipLaunchKernelGGL(k_corr2, dim3(512), dim3(256), 0, stream, SH, M2N, MP2N, MM2N, dp, PG);
        hipLaunchKernelGGL(k_update, dim3(256), dim3(256), 0, stream, x, PG, QG, gp, qdst);
        qsrc = qdst;
    }
}